// Round 1
// 1307.721 us; speedup vs baseline: 1.1112x; 1.1112x over previous
//
#include <hip/hip_runtime.h>
#include <stdint.h>

// Shapes
#define VOCAB 32000
#define EMBED 256
#define H1DIM 512
#define KVDIM 128
#define BB    32
#define SS    512
#define TT    256
#define MTOT  (BB*TT)   // 8192

typedef __attribute__((ext_vector_type(8))) short    short8;
typedef __attribute__((ext_vector_type(4))) float    floatx4;
typedef __attribute__((ext_vector_type(8))) _Float16 half8;
typedef __attribute__((ext_vector_type(4))) _Float16 half4;

__device__ __forceinline__ unsigned short f2bf(float f){
  unsigned int x = __float_as_uint(f);
  x += 0x7fffu + ((x >> 16) & 1u);          // round-nearest-even to bf16
  return (unsigned short)(x >> 16);
}
__device__ __forceinline__ float sigm(float x){ return __fdividef(1.0f, 1.0f + __expf(-x)); }
// guarded fast tanh: exp(2x)=inf -> 1, exp(2x)=0 -> -1 (no inf/inf NaN)
__device__ __forceinline__ float ftanh(float x){
  float e = __expf(2.0f*x);
  return 1.0f - __fdividef(2.0f, e + 1.0f);
}

__device__ __forceinline__ void async_lds16(const void* g, void* s){
  typedef const __attribute__((address_space(1))) unsigned int* gp_t;
  typedef __attribute__((address_space(3))) unsigned int* lp_t;
  __builtin_amdgcn_global_load_lds((gp_t)g, (lp_t)s, 16, 0, 0);
}

// ---------------- kernel: f32 -> bf16 (for tied-weight output GEMM) ----------------
__global__ __launch_bounds__(256) void cvt_kernel(const float* __restrict__ src,
                                                  unsigned short* __restrict__ dst, int n4){
  int i = blockIdx.x*256 + threadIdx.x;
  if (i >= n4) return;
  float4 v = ((const float4*)src)[i];
  ushort4 o;
  o.x = f2bf(v.x); o.y = f2bf(v.y); o.z = f2bf(v.z); o.w = f2bf(v.w);
  ((ushort4*)dst)[i] = o;
}

// ---------------- kernel: f32 -> f16 (LSTM weights; fp16 keeps 8x more mantissa than bf16) ----
__global__ __launch_bounds__(256) void cvt16_kernel(const float* __restrict__ src,
                                                    _Float16* __restrict__ dst, int n4){
  int i = blockIdx.x*256 + threadIdx.x;
  if (i >= n4) return;
  float4 v = ((const float4*)src)[i];
  half4 o;
  o[0] = (_Float16)v.x; o[1] = (_Float16)v.y; o[2] = (_Float16)v.z; o[3] = (_Float16)v.w;
  ((half4*)dst)[i] = o;
}

// ---------------- kernel: gather token embeddings -> f16 matrix (8192 x 256) ----------------
// 32 threads per row, 8 elems/thread. Row m=(b,t): token = (t==0)?0:y[b,t-1].
__global__ __launch_bounds__(256) void gather16_kernel(const float* __restrict__ E,
    const int* __restrict__ y, _Float16* __restrict__ out){
  int g = blockIdx.x*256 + threadIdx.x;     // 0..262143
  int m = g >> 5;
  int e = (g & 31) * 8;
  int t = m & (TT-1), bb = m >> 8;
  int tok = (t == 0) ? 0 : y[bb*TT + t - 1];
  const float* src = E + (size_t)tok*EMBED + e;
  float4 v0 = *(const float4*)src;
  float4 v1 = *(const float4*)(src + 4);
  half8 h;
  h[0]=(_Float16)v0.x; h[1]=(_Float16)v0.y; h[2]=(_Float16)v0.z; h[3]=(_Float16)v0.w;
  h[4]=(_Float16)v1.x; h[5]=(_Float16)v1.y; h[6]=(_Float16)v1.z; h[7]=(_Float16)v1.w;
  *(half8*)(out + (size_t)m*EMBED + e) = h;
}

// ---------------- LSTM-cell GEMM via f16 MFMA (m97 structure) ----------------
// Tile: 128 m-rows x 64 j-units x 3 gates (i,g,o; f-gate inert at zero state).
// 4 waves: wv=(w&1)*64 m-half, wj=(w>>1)*32 j-half. 24 MFMA/wave/k-step.
// h = sigmoid(o) * tanh( sigmoid(i) * tanh(g) )
template<int K, int RI, int RG, int RO, int OSTRIDE, bool OF16>
__global__ __launch_bounds__(256) void lstm_mfma_kernel(
    const _Float16* __restrict__ A16, const _Float16* __restrict__ W16,
    const float* __restrict__ b_ih, const float* __restrict__ b_hh,
    void* __restrict__ Hout)
{
  __shared__ __align__(16) char smem[20480];
  char* As = smem;            // A tile: 128 rows x 32 f16 (64B rows) = 8 KB
  char* Bs = smem + 8192;     // W tiles: 3 gates x 64 rows x 64B = 12 KB

  const int tid  = threadIdx.x;
  const int lane = tid & 63, w = tid >> 6;
  const int j0 = blockIdx.x * 64;
  const int m0 = blockIdx.y * 128;

  const int r0 = tid >> 2;            // staging row 0..63 (tid*16 == r0*64+cb)
  const int cb = (tid & 3) * 16;      // byte chunk within 64B row

  const char* asrc0 = (const char*)A16 + (size_t)(m0 + r0     ) * (K*2);
  const char* asrc1 = (const char*)A16 + (size_t)(m0 + r0 + 64) * (K*2);
  const char* bsrc0 = (const char*)W16 + (size_t)(RI + j0 + r0) * (K*2);
  const char* bsrc1 = (const char*)W16 + (size_t)(RG + j0 + r0) * (K*2);
  const char* bsrc2 = (const char*)W16 + (size_t)(RO + j0 + r0) * (K*2);

  char* ldsA0 = As        + w*1024;   // wave-uniform base; HW adds lane*16
  char* ldsA1 = As + 4096 + w*1024;
  char* ldsB0 = Bs        + w*1024;
  char* ldsB1 = Bs + 4096 + w*1024;
  char* ldsB2 = Bs + 8192 + w*1024;

  const int wv = (w & 1) * 64;
  const int wj = (w >> 1) * 32;

  floatx4 zero = {0.f,0.f,0.f,0.f};
  floatx4 acc[4][2][3];
  #pragma unroll
  for (int a=0;a<4;a++)
    #pragma unroll
    for (int b=0;b<2;b++)
      #pragma unroll
      for (int g=0;g<3;g++) acc[a][b][g] = zero;

  const int fr = lane & 15;           // fragment row
  const int fo = (lane >> 4) * 16;    // k-fragment byte offset (8 f16)

  for (int kt = 0; kt < K/32; kt++){
    const int ko = kt*64 + cb;
    async_lds16(asrc0 + ko, ldsA0);
    async_lds16(asrc1 + ko, ldsA1);
    async_lds16(bsrc0 + ko, ldsB0);
    async_lds16(bsrc1 + ko, ldsB1);
    async_lds16(bsrc2 + ko, ldsB2);
    __syncthreads();   // drains vmcnt -> tiles resident

    half8 af[4], bfr[2][3];
    #pragma unroll
    for (int i=0;i<4;i++)
      af[i] = *(const half8*)(As + (wv + i*16 + fr)*64 + fo);
    #pragma unroll
    for (int ji=0;ji<2;ji++)
      #pragma unroll
      for (int g=0;g<3;g++)
        bfr[ji][g] = *(const half8*)(Bs + g*4096 + (wj + ji*16 + fr)*64 + fo);
    #pragma unroll
    for (int mi=0;mi<4;mi++)
      #pragma unroll
      for (int ji=0;ji<2;ji++)
        #pragma unroll
        for (int g=0;g<3;g++)
          acc[mi][ji][g] = __builtin_amdgcn_mfma_f32_16x16x32_f16(
              af[mi], bfr[ji][g], acc[mi][ji][g], 0, 0, 0);
    __syncthreads();   // reads done before next stage overwrites
  }

  // epilogue: D col(lane&15)=j (W side), row((lane>>4)*4+r)=m (A side)
  #pragma unroll
  for (int ji=0;ji<2;ji++){
    const int j = j0 + wj + ji*16 + fr;
    const float bI = b_ih[RI+j] + b_hh[RI+j];
    const float bG = b_ih[RG+j] + b_hh[RG+j];
    const float bO = b_ih[RO+j] + b_hh[RO+j];
    #pragma unroll
    for (int mi=0;mi<4;mi++){
      const int mb = m0 + wv + mi*16 + (lane>>4)*4;
      #pragma unroll
      for (int r=0;r<4;r++){
        float iv = sigm(acc[mi][ji][0][r] + bI);
        float gv = ftanh(acc[mi][ji][1][r] + bG);
        float ov = sigm(acc[mi][ji][2][r] + bO);
        float h  = ov * ftanh(iv * gv);
        if constexpr (OF16)
          ((_Float16*)Hout)[(size_t)(mb + r)*OSTRIDE + j] = (_Float16)h;
        else
          ((float*)Hout)[(size_t)(mb + r)*OSTRIDE + j] = h;
      }
    }
  }
}

// ---------------- attention: energy -> masked softmax -> context; emits out_ctx bf16 ----------------
// block = (b, 16-token t-tile); 512 blocks x 256 threads
__global__ __launch_bounds__(256) void attn_kernel(
    const float* __restrict__ key, const float* __restrict__ value,
    const int* __restrict__ enc_len, const float* __restrict__ h2,
    unsigned short* __restrict__ oc)
{
  __shared__ __align__(16) float h2s[16][128];   // 8 KB
  __shared__ __align__(16) float kst[128][36];   // key chunk transposed [c][s_local], 18 KB
  __shared__ __align__(16) float es[16][512];    // 32 KB
  __shared__ float red[16][17];
  __shared__ float rmax[16], rsinv[16];

  const int tid = threadIdx.x;
  const int b   = blockIdx.x >> 4;
  const int t0  = (blockIdx.x & 15) * 16;
  const int L   = enc_len[b];

  { // load h2 tile + emit left half of out_ctx (bf16)
    int r = tid >> 4, c0 = (tid & 15) * 8;
    const float* src = h2 + ((size_t)(b*TT + t0 + r))*KVDIM + c0;
    float4 v0 = *(const float4*)src;
    float4 v1 = *(const float4*)(src + 4);
    *(float4*)&h2s[r][c0]   = v0;
    *(float4*)&h2s[r][c0+4] = v1;
    unsigned short* od = oc + ((size_t)(b*TT + t0 + r))*EMBED + c0;
    od[0]=f2bf(v0.x); od[1]=f2bf(v0.y); od[2]=f2bf(v0.z); od[3]=f2bf(v0.w);
    od[4]=f2bf(v1.x); od[5]=f2bf(v1.y); od[6]=f2bf(v1.z); od[7]=f2bf(v1.w);
  }

  const int ksr = tid >> 3, kcg = tid & 7;    // staging: 32 rows x 8 col-groups
  const int sl  = tid & 31, g = tid >> 5;     // energy: 32 s x 8 groups (2 tt each)
  const int tb  = g*2;

  for (int s0 = 0; s0 < SS; s0 += 32){
    __syncthreads();
    { // stage key[s0..s0+31][:] transposed
      const float* kr = key + ((size_t)(b*SS + s0 + ksr))*KVDIM;
      #pragma unroll
      for (int u=0; u<4; u++){
        int c = u*32 + kcg*4;
        float4 kv = *(const float4*)(kr + c);
        kst[c+0][ksr]=kv.x; kst[c+1][ksr]=kv.y; kst[c+2][ksr]=kv.z; kst[c+3][ksr]=kv.w;
      }
    }
    __syncthreads();
    float a0=0.f, a1=0.f;
    #pragma unroll 4
    for (int c=0;c<128;c+=4){
      float k0v=kst[c][sl], k1v=kst[c+1][sl], k2v=kst[c+2][sl], k3v=kst[c+3][sl];
      float4 h0 = *(const float4*)&h2s[tb][c];
      float4 h1 = *(const float4*)&h2s[tb+1][c];
      a0 = fmaf(k0v,h0.x, fmaf(k1v,h0.y, fmaf(k2v,h0.z, fmaf(k3v,h0.w, a0))));
      a1 = fmaf(k0v,h1.x, fmaf(k1v,h1.y, fmaf(k2v,h1.z, fmaf(k3v,h1.w, a1))));
    }
    int s = s0 + sl;
    bool valid = s < L;
    es[tb  ][s] = valid ? a0 : -1e9f;
    es[tb+1][s] = valid ? a1 : -1e9f;
  }
  __syncthreads();

  { // masked softmax per row (16 threads/row)
    int row = tid >> 4, l = tid & 15;
    float mx = -3e38f;
    for (int s=l; s<SS; s+=16) mx = fmaxf(mx, es[row][s]);
    red[row][l] = mx;
    __syncthreads();
    if (l == 0){
      float m2 = -3e38f;
      #pragma unroll
      for (int i=0;i<16;i++) m2 = fmaxf(m2, red[row][i]);
      rmax[row] = m2;
    }
    __syncthreads();
    float m = rmax[row], sum = 0.f;
    for (int s=l; s<SS; s+=16){
      float p = __expf(es[row][s] - m);   // masked -> exp(-1e9-m) == 0
      es[row][s] = p;
      sum += p;
    }
    red[row][l] = sum;
    __syncthreads();
    if (l == 0){
      float tsum = 0.f;
      #pragma unroll
      for (int i=0;i<16;i++) tsum += red[row][i];
      rsinv[row] = 1.0f / tsum;
    }
    __syncthreads();
  }

  { // context = P @ value, emit right half of out_ctx (bf16)
    int v = tid & 127, hh = tid >> 7;
    float acc[8] = {0,0,0,0,0,0,0,0};
    const float* vp = value + ((size_t)b*SS)*KVDIM + v;
    #pragma unroll 2
    for (int s=0; s<SS; s+=4){
      float x0 = vp[(size_t)(s+0)*KVDIM];
      float x1 = vp[(size_t)(s+1)*KVDIM];
      float x2 = vp[(size_t)(s+2)*KVDIM];
      float x3 = vp[(size_t)(s+3)*KVDIM];
      #pragma unroll
      for (int i=0;i<8;i++){
        float4 e = *(const float4*)&es[hh*8+i][s];
        acc[i] = fmaf(e.x,x0, fmaf(e.y,x1, fmaf(e.z,x2, fmaf(e.w,x3, acc[i]))));
      }
    }
    #pragma unroll
    for (int i=0;i<8;i++){
      int tt = hh*8 + i;
      oc[((size_t)(b*TT + t0 + tt))*EMBED + KVDIM + v] = f2bf(acc[i] * rsinv[tt]);
    }
  }
}

// ---------------- final GEMM: out[b][v][t] = [h2,ctx](b,t,:) . E[v,:] + b_out[v] ----------------
// bf16 MFMA 16x16x32, 128x128 tile, 4 waves of 64x64, global_load_lds staging (m97 structure).
// 1-D grid with chunk swizzle: 512-block chunks = 8 v-tiles x all 64 (t,b) tiles, so each
// 64KB E tile is reused 64x while L2-resident (E L3 streaming 1.05GB -> ~150MB).
__global__ __launch_bounds__(256) void out_gemm_kernel(
    const unsigned short* __restrict__ Ebf, const unsigned short* __restrict__ OC,
    const float* __restrict__ b_out, float* __restrict__ out)
{
  __shared__ __align__(16) char smem[16384];
  char* As = smem;          // E tile: 128 rows(v) x 32 bf16 (64B rows)
  char* Bs = smem + 8192;   // out_ctx tile: 128 rows(t) x 32 bf16

  const int tid  = threadIdx.x;
  const int lane = tid & 63, w = tid >> 6;

  // chunk swizzle (16000 blocks = 31 full chunks of 512 + 1 chunk of 128)
  const int id     = blockIdx.x;
  const int chunk  = id >> 9;
  const int within = id & 511;
  const int vt = (chunk << 3) + (within >> 6);  // v-tile 0..249
  const int tb = within & 63;                   // (t,b) tile 0..63
  const int v0 = vt * 128;
  const int t0 = (tb & 1) * 128;
  const int b  = tb >> 1;

  const int wv = (w & 1) * 64, wt = (w >> 1) * 64;

  const char* Ab = (const char*)Ebf + (size_t)v0 * (EMBED*2);
  const char* Bb = (const char*)OC  + ((size_t)(b*TT + t0)) * (EMBED*2);

  const int r0 = tid >> 2;            // staging row (q=0); q=1 adds 64
  const int cb = (tid & 3) * 16;      // byte offset within 64B row chunk
  char* ldsA0 = As        + w * 1024; // wave-uniform base; HW adds lane*16
  char* ldsA1 = As + 4096 + w * 1024;
  char* ldsB0 = Bs        + w * 1024;
  char* ldsB1 = Bs + 4096 + w * 1024;

  floatx4 zero = {0.f, 0.f, 0.f, 0.f};
  floatx4 acc[4][4];
  #pragma unroll
  for (int i=0;i<4;i++)
    #pragma unroll
    for (int j=0;j<4;j++) acc[i][j] = zero;

  const int fr = lane & 15;           // row within 16
  const int fo = (lane >> 4) * 16;    // k-fragment byte offset (8 bf16)

  for (int kt = 0; kt < 8; kt++){
    const size_t ko = (size_t)kt * 64;
    async_lds16(Ab + (size_t)(r0     )*512 + ko + cb, ldsA0);
    async_lds16(Ab + (size_t)(r0 + 64)*512 + ko + cb, ldsA1);
    async_lds16(Bb + (size_t)(r0     )*512 + ko + cb, ldsB0);
    async_lds16(Bb + (size_t)(r0 + 64)*512 + ko + cb, ldsB1);
    __syncthreads();   // drains vmcnt before barrier -> tiles resident

    short8 af[4], bq[4];
    #pragma unroll
    for (int i=0;i<4;i++) af[i] = *(const short8*)(As + (wv + i*16 + fr)*64 + fo);
    #pragma unroll
    for (int j=0;j<4;j++) bq[j] = *(const short8*)(Bs + (wt + j*16 + fr)*64 + fo);
    #pragma unroll
    for (int i=0;i<4;i++)
      #pragma unroll
      for (int j=0;j<4;j++)
        acc[i][j] = __builtin_amdgcn_mfma_f32_16x16x32_bf16(af[i], bq[j], acc[i][j], 0, 0, 0);
    __syncthreads();   // reads done before next stage overwrites
  }

  // epilogue: D col(lane&15)=t, row((lane>>4)*4+reg)=v
  const int tc = t0 + wt + fr;
  #pragma unroll
  for (int i=0;i<4;i++){
    int vb = v0 + wv + i*16 + (lane >> 4)*4;
    #pragma unroll
    for (int r=0;r<4;r++){
      int v = vb + r;
      float bo = b_out[v];
      float* orow = out + ((size_t)b*VOCAB + v)*TT + tc;
      #pragma unroll
      for (int j=0;j<4;j++)
        orow[j*16] = acc[i][j][r] + bo;
    }
  }
}

extern "C" void kernel_launch(void* const* d_in, const int* in_sizes, int n_in,
                              void* d_out, int out_size, void* d_ws, size_t ws_size,
                              hipStream_t stream) {
  const float* key   = (const float*)d_in[0];
  const float* value = (const float*)d_in[1];
  const int*   elen  = (const int*)  d_in[2];
  const int*   y     = (const int*)  d_in[3];
  const float* E     = (const float*)d_in[4];
  const float* W1    = (const float*)d_in[5];
  const float* bi1   = (const float*)d_in[6];
  const float* bh1   = (const float*)d_in[7];
  const float* W2    = (const float*)d_in[8];
  const float* bi2   = (const float*)d_in[9];
  const float* bh2   = (const float*)d_in[10];
  const float* bo    = (const float*)d_in[11];
  float* out = (float*)d_out;

  char* ws = (char*)d_ws;
  _Float16*       h1f   = (_Float16*)ws;                            // 8192*512*2  =  8,388,608
  _Float16*       W1f   = (_Float16*)(ws + 8388608);                // 2048*256*2  =  1,048,576
  _Float16*       W2f   = (_Float16*)(ws + 9437184);                // 512*512*2   =    524,288
  _Float16*       Emb16 = (_Float16*)(ws + 9961472);                // 8192*256*2  =  4,194,304
  float*          h2    = (float*)(ws + 16777216);                  // 8192*128*4  =  4,194,304
  unsigned short* Ebf   = (unsigned short*)(ws + 20971520);         // 32000*256*2 = 16,384,000
  unsigned short* OC    = (unsigned short*)(ws + 37355520);         // 8192*256*2  =  4,194,304

  // 1) conversions: E -> bf16 (output GEMM), W1/W2 -> f16, token embeddings -> f16
  cvt_kernel  <<<8000, 256, 0, stream>>>(E,  Ebf, (VOCAB*EMBED)/4);
  cvt16_kernel<<< 512, 256, 0, stream>>>(W1, W1f, (4*H1DIM*EMBED)/4);
  cvt16_kernel<<< 256, 256, 0, stream>>>(W2, W2f, (4*KVDIM*H1DIM)/4);
  gather16_kernel<<<1024, 256, 0, stream>>>(E, y, Emb16);
  // 2) layer 1 LSTM-cell GEMM (f16 MFMA) -> h1 (f16)
  lstm_mfma_kernel<256, 0, 1024, 1536, 512, true>
      <<<dim3(8, 64), 256, 0, stream>>>(Emb16, W1f, bi1, bh1, h1f);
  // 3) layer 2 -> h2 (f32)
  lstm_mfma_kernel<512, 0, 256, 384, 128, false>
      <<<dim3(2, 64), 256, 0, stream>>>(h1f, W2f, bi2, bh2, h2);
  // 4) attention -> out_ctx bf16 (both halves)
  attn_kernel<<<512, 256, 0, stream>>>(key, value, elen, h2, OC);
  // 5) tied-weight output GEMM (bf16 MFMA, chunk-swizzled grid) -> transposed logits
  out_gemm_kernel<<<16000, 256, 0, stream>>>(Ebf, OC, bo, out);
}